// Round 9
// baseline (620.027 us; speedup 1.0000x reference)
//
#include <hip/hip_runtime.h>
#include <hip/hip_bf16.h>

// FraudGNN: 3x SAGEConv(mean) + ReLU + linear classifier.
// Structure: transform-then-aggregate; CSR build (1 atomic pass); gather-side
// aggregation; classifier fused into layer-3 agg.
// R6 counters (only successful bench): gemm_dual<128> top dispatch (101us),
//   VALUBusy 52%, Occ 19.5% (LDS 74KB -> 2 blocks/CU), latency-bound.
// R7 fix (resubmitted verbatim in R8/R9 after GPU timeouts):
//   - X tile LDS + per-tile barriers removed: X read as wave-uniform broadcast
//     float4 directly from global (L1-resident row), barrier-free main loop.
//   - 512-thr blocks, 8 rows/thread, LDS = W only (66KB K=128 / 33KB K=64)
//     -> 16 waves/CU. 8 independent loads in flight per kq.

// ---------------- degree count + slot assignment (single atomic pass) --------
__global__ __launch_bounds__(256) void count_deg_slot(const int* __restrict__ dst,
                                                      int* __restrict__ deg,
                                                      int* __restrict__ eslot, int nE) {
    int e = blockIdx.x * 256 + threadIdx.x;
    if (e < nE) eslot[e] = atomicAdd(&deg[dst[e]], 1);
}

// ---------------- 3-phase exclusive scan over deg (N<=2048*256) ----------------
__global__ __launch_bounds__(256) void scan_partial(const int* __restrict__ deg,
                                                    int* __restrict__ partial, int n) {
    __shared__ int red[256];
    int base = blockIdx.x * 2048;
    int t = threadIdx.x;
    int sum = 0;
    for (int j = 0; j < 8; ++j) {
        int i = base + t + 256 * j;
        if (i < n) sum += deg[i];
    }
    red[t] = sum;
    __syncthreads();
    for (int o = 128; o; o >>= 1) {
        if (t < o) red[t] += red[t + o];
        __syncthreads();
    }
    if (t == 0) partial[blockIdx.x] = red[0];
}

__global__ __launch_bounds__(256) void scan_block(int* __restrict__ partial, int B) {
    __shared__ int tmp[256];
    int t = threadIdx.x;
    int orig = (t < B) ? partial[t] : 0;
    tmp[t] = orig;
    __syncthreads();
    for (int o = 1; o < 256; o <<= 1) {
        int v = (t >= o) ? tmp[t - o] : 0;
        __syncthreads();
        tmp[t] += v;
        __syncthreads();
    }
    if (t < B) partial[t] = tmp[t] - orig;  // exclusive
}

__global__ __launch_bounds__(256) void scan_final(const int* __restrict__ deg,
                                                  const int* __restrict__ partial,
                                                  int* __restrict__ off,
                                                  float* __restrict__ deg_inv, int n) {
    __shared__ int lds[2048];
    __shared__ int tsum[256];
    int base = blockIdx.x * 2048;
    int t = threadIdx.x;
    for (int j = 0; j < 8; ++j) {
        int i = base + t + 256 * j;
        lds[t + 256 * j] = (i < n) ? deg[i] : 0;
    }
    __syncthreads();
    int loc[8];
    int s0 = 0;
    for (int j = 0; j < 8; ++j) {
        loc[j] = s0;
        s0 += lds[t * 8 + j];
    }
    int orig = s0;
    tsum[t] = s0;
    __syncthreads();
    for (int o = 1; o < 256; o <<= 1) {
        int v = (t >= o) ? tsum[t - o] : 0;
        __syncthreads();
        tsum[t] += v;
        __syncthreads();
    }
    int tpre = tsum[t] - orig + partial[blockIdx.x];
    for (int j = 0; j < 8; ++j) {
        int i = base + t * 8 + j;
        if (i < n) {
            int d = lds[t * 8 + j];
            int ex = tpre + loc[j];
            off[i] = ex;
            deg_inv[i] = 1.0f / (float)((d > 1) ? d : 1);
            if (i == n - 1) off[n] = ex + d;
        }
    }
}

// ---------------- CSR fill (atomic-free: slot precomputed) ----------------
__global__ __launch_bounds__(256) void fill_csr(const int* __restrict__ src,
                                                const int* __restrict__ dst,
                                                const int* __restrict__ off,
                                                const int* __restrict__ eslot,
                                                int* __restrict__ csr, int nE) {
    int e = blockIdx.x * 256 + threadIdx.x;
    if (e >= nE) return;
    csr[off[dst[e]] + eslot[e]] = src[e];
}

// ---------------- dual GEMM: Y = X @ Wl^T ; S = X @ Wr^T + bl ----------------
// X:[n,K], Wl/Wr:[64,K], Y/S:[n,64].
// 512 threads = 64 features x 8 row-slots; 8 rows/thread -> 64 rows/tile.
// LDS: W only, [64][K+1] (bank (f+k)%32 -> 2-way across 64 lanes = free, m136).
// X read as wave-uniform float4 broadcast from global (row L1-resident),
// main loop barrier-free. 8 independent loads in flight per kq.
template <int K>
__global__ __launch_bounds__(512, 4) void gemm_dual(const float* __restrict__ X,
                                                    const float* __restrict__ Wl,
                                                    const float* __restrict__ Wr,
                                                    const float* __restrict__ bl,
                                                    float* __restrict__ Y,
                                                    float* __restrict__ S, int nNodes) {
    __shared__ float wl_s[64][K + 1];
    __shared__ float wr_s[64][K + 1];
    const int t = threadIdx.x;
    for (int i = t; i < 64 * K; i += 512) {
        int f = i / K, k = i % K;
        wl_s[f][k] = Wl[i];
        wr_s[f][k] = Wr[i];
    }
    const int f = t & 63;        // output feature
    const int s = t >> 6;        // row slot 0..7 (== wave id)
    __syncthreads();
    const float blf = bl[f];
    const float4* __restrict__ Xv = reinterpret_cast<const float4*>(X);
    constexpr int KQ = K / 4;
    const int nTiles = (nNodes + 63) >> 6;

    for (int tb = blockIdx.x; tb < nTiles; tb += gridDim.x) {
        const int r0 = tb * 64 + s * 8;
        size_t xb[8];
#pragma unroll
        for (int j = 0; j < 8; ++j) {
            int rc = r0 + j;
            rc = (rc < nNodes) ? rc : (nNodes - 1);  // clamp: safe load, store guarded
            xb[j] = (size_t)rc * KQ;
        }
        float accY[8] = {0.f, 0.f, 0.f, 0.f, 0.f, 0.f, 0.f, 0.f};
        float accS[8] = {0.f, 0.f, 0.f, 0.f, 0.f, 0.f, 0.f, 0.f};
#pragma unroll 2
        for (int kq = 0; kq < KQ; ++kq) {
            float4 xr[8];
#pragma unroll
            for (int j = 0; j < 8; ++j) xr[j] = Xv[xb[j] + kq];  // wave-uniform bcast
            const int k0 = 4 * kq;
            float wl0 = wl_s[f][k0 + 0], wl1 = wl_s[f][k0 + 1];
            float wl2 = wl_s[f][k0 + 2], wl3 = wl_s[f][k0 + 3];
            float wr0 = wr_s[f][k0 + 0], wr1 = wr_s[f][k0 + 1];
            float wr2 = wr_s[f][k0 + 2], wr3 = wr_s[f][k0 + 3];
#pragma unroll
            for (int j = 0; j < 8; ++j) {
                accY[j] = fmaf(xr[j].x, wl0, accY[j]);
                accY[j] = fmaf(xr[j].y, wl1, accY[j]);
                accY[j] = fmaf(xr[j].z, wl2, accY[j]);
                accY[j] = fmaf(xr[j].w, wl3, accY[j]);
                accS[j] = fmaf(xr[j].x, wr0, accS[j]);
                accS[j] = fmaf(xr[j].y, wr1, accS[j]);
                accS[j] = fmaf(xr[j].z, wr2, accS[j]);
                accS[j] = fmaf(xr[j].w, wr3, accS[j]);
            }
        }
        if (r0 + 7 < nNodes) {
#pragma unroll
            for (int j = 0; j < 8; ++j) {
                Y[(size_t)(r0 + j) * 64 + f] = accY[j];
                S[(size_t)(r0 + j) * 64 + f] = accS[j] + blf;
            }
        } else {
#pragma unroll
            for (int j = 0; j < 8; ++j) {
                if (r0 + j < nNodes) {
                    Y[(size_t)(r0 + j) * 64 + f] = accY[j];
                    S[(size_t)(r0 + j) * 64 + f] = accS[j] + blf;
                }
            }
        }
    }
}

// ---------------- aggregation core: sum_neighbors(Y) as float4 ----------------
// wave = 16 feature-quads x 4 edge-quarters. Quarter q reads row src[4j+q] as
// float4 (16 lanes x 16 B = 256 B, coalesced). ILP ladder: x4-unrolled block
// (4 loads in flight), then x2, then x1.
__device__ __forceinline__ float4 agg_core(const float4* __restrict__ Yv,
                                           const int* __restrict__ csr,
                                           int e0, int e1, int lane) {
    const int q = lane >> 4;         // edge quarter 0..3
    const int fq = lane & 15;        // feature quad
    float4 acc = make_float4(0.f, 0.f, 0.f, 0.f);
    for (int base = e0; base < e1; base += 64) {
        int cnt = min(64, e1 - base);
        int mysrc = (lane < cnt) ? csr[base + lane] : 0;
        int nFull = cnt >> 2;
        int j = 0;
        for (; j + 4 <= nFull; j += 4) {   // 4 outstanding dwordx4 loads
            int s0 = __shfl(mysrc, 4 * j + q);
            int s1 = __shfl(mysrc, 4 * j + 4 + q);
            int s2 = __shfl(mysrc, 4 * j + 8 + q);
            int s3 = __shfl(mysrc, 4 * j + 12 + q);
            float4 v0 = Yv[(size_t)s0 * 16 + fq];
            float4 v1 = Yv[(size_t)s1 * 16 + fq];
            float4 v2 = Yv[(size_t)s2 * 16 + fq];
            float4 v3 = Yv[(size_t)s3 * 16 + fq];
            acc.x += v0.x; acc.y += v0.y; acc.z += v0.z; acc.w += v0.w;
            acc.x += v1.x; acc.y += v1.y; acc.z += v1.z; acc.w += v1.w;
            acc.x += v2.x; acc.y += v2.y; acc.z += v2.z; acc.w += v2.w;
            acc.x += v3.x; acc.y += v3.y; acc.z += v3.z; acc.w += v3.w;
        }
        if (j + 2 <= nFull) {              // 2 outstanding
            int s0 = __shfl(mysrc, 4 * j + q);
            int s1 = __shfl(mysrc, 4 * j + 4 + q);
            float4 v0 = Yv[(size_t)s0 * 16 + fq];
            float4 v1 = Yv[(size_t)s1 * 16 + fq];
            acc.x += v0.x; acc.y += v0.y; acc.z += v0.z; acc.w += v0.w;
            acc.x += v1.x; acc.y += v1.y; acc.z += v1.z; acc.w += v1.w;
            j += 2;
        }
        if (j < nFull) {                   // last full quad
            int sj = __shfl(mysrc, 4 * j + q);
            float4 v = Yv[(size_t)sj * 16 + fq];
            acc.x += v.x; acc.y += v.y; acc.z += v.z; acc.w += v.w;
        }
        int rem = cnt & 3;
        if (rem) {
            int sj = __shfl(mysrc, 4 * nFull + q);  // idx <= 63 always
            if (q < rem) {
                float4 v = Yv[(size_t)sj * 16 + fq];
                acc.x += v.x; acc.y += v.y; acc.z += v.z; acc.w += v.w;
            }
        }
    }
    // combine quarter partials: after xor16 + xor32 every lane has the full sum
    acc.x += __shfl_xor(acc.x, 16); acc.y += __shfl_xor(acc.y, 16);
    acc.z += __shfl_xor(acc.z, 16); acc.w += __shfl_xor(acc.w, 16);
    acc.x += __shfl_xor(acc.x, 32); acc.y += __shfl_xor(acc.y, 32);
    acc.z += __shfl_xor(acc.z, 32); acc.w += __shfl_xor(acc.w, 32);
    return acc;  // lanes 0-15 used for epilogue (feature quad fq)
}

// ---------------- aggregation: H = relu(mean_neighbors(Y) + S) ----------------
__global__ __launch_bounds__(256) void agg_relu(const float* __restrict__ Y,
                                                const float* __restrict__ S,
                                                const int* __restrict__ csr,
                                                const int* __restrict__ off,
                                                const float* __restrict__ deg_inv,
                                                float* __restrict__ H, int nNodes) {
    int wave = threadIdx.x >> 6;
    int lane = threadIdx.x & 63;
    int n = blockIdx.x * 4 + wave;
    if (n >= nNodes) return;
    int e0 = off[n], e1 = off[n + 1];
    // prefetch epilogue operands: independent of the gather, hide under it
    float di = deg_inv[n];
    float4 sv = ((const float4*)S)[(size_t)n * 16 + (lane & 15)];
    float4 acc = agg_core((const float4*)Y, csr, e0, e1, lane);
    if (lane < 16) {
        float4 h;
        h.x = fmaxf(fmaf(acc.x, di, sv.x), 0.f);
        h.y = fmaxf(fmaf(acc.y, di, sv.y), 0.f);
        h.z = fmaxf(fmaf(acc.z, di, sv.z), 0.f);
        h.w = fmaxf(fmaf(acc.w, di, sv.w), 0.f);
        ((float4*)H)[(size_t)n * 16 + lane] = h;
    }
}

// ---------------- layer-3 aggregation + classifier fused ----------------
__global__ __launch_bounds__(256) void agg_classify(const float* __restrict__ Y,
                                                    const float* __restrict__ S,
                                                    const int* __restrict__ csr,
                                                    const int* __restrict__ off,
                                                    const float* __restrict__ deg_inv,
                                                    const float* __restrict__ Wc,
                                                    const float* __restrict__ bc,
                                                    float* __restrict__ out, int nNodes) {
    int wave = threadIdx.x >> 6;
    int lane = threadIdx.x & 63;
    int n = blockIdx.x * 4 + wave;
    if (n >= nNodes) return;
    int e0 = off[n], e1 = off[n + 1];
    float di = deg_inv[n];
    float4 sv = ((const float4*)S)[(size_t)n * 16 + (lane & 15)];
    float4 wc = ((const float4*)Wc)[lane & 15];
    float bias = bc[0];
    float4 acc = agg_core((const float4*)Y, csr, e0, e1, lane);
    if (lane < 16) {
        float hx = fmaxf(fmaf(acc.x, di, sv.x), 0.f);
        float hy = fmaxf(fmaf(acc.y, di, sv.y), 0.f);
        float hz = fmaxf(fmaf(acc.z, di, sv.z), 0.f);
        float hw = fmaxf(fmaf(acc.w, di, sv.w), 0.f);
        float c = hx * wc.x + hy * wc.y + hz * wc.z + hw * wc.w;
#pragma unroll
        for (int o = 8; o; o >>= 1) c += __shfl_xor(c, o);  // within 16-lane group
        if (lane == 0) out[n] = c + bias;
    }
}

extern "C" void kernel_launch(void* const* d_in, const int* in_sizes, int n_in,
                              void* d_out, int out_size, void* d_ws, size_t ws_size,
                              hipStream_t stream) {
    const float* x   = (const float*)d_in[0];
    const int*   ei  = (const int*)d_in[1];
    const float* Wl1 = (const float*)d_in[2];
    const float* bl1 = (const float*)d_in[3];
    const float* Wr1 = (const float*)d_in[4];
    const float* Wl2 = (const float*)d_in[5];
    const float* bl2 = (const float*)d_in[6];
    const float* Wr2 = (const float*)d_in[7];
    const float* Wl3 = (const float*)d_in[8];
    const float* bl3 = (const float*)d_in[9];
    const float* Wr3 = (const float*)d_in[10];
    const float* Wc  = (const float*)d_in[11];
    const float* bc  = (const float*)d_in[12];
    float* out = (float*)d_out;

    const int N = in_sizes[0] / 128;   // 100000
    const int E = in_sizes[1] / 2;     // 1600000
    const int* src = ei;
    const int* dst = ei + E;

    // workspace carve (256B aligned); total ~91 MB
    char* p = (char*)d_ws;
    auto alloc = [&](size_t bytes) -> void* {
        char* r = p;
        p += (bytes + 255) & ~(size_t)255;
        return (void*)r;
    };
    int*   deg     = (int*)alloc((size_t)N * 4);
    int*   off     = (int*)alloc((size_t)(N + 1) * 4);
    int*   eslot   = (int*)alloc((size_t)E * 4);
    int*   partial = (int*)alloc(256 * 4);
    int*   csr     = (int*)alloc((size_t)E * 4);
    float* deg_inv = (float*)alloc((size_t)N * 4);
    float* y       = (float*)alloc((size_t)N * 64 * 4);
    float* s       = (float*)alloc((size_t)N * 64 * 4);
    float* h       = (float*)alloc((size_t)N * 64 * 4);

    hipMemsetAsync(deg, 0, (size_t)N * 4, stream);

    const int B = (N + 2047) / 2048;  // 49 scan blocks

    count_deg_slot<<<(E + 255) / 256, 256, 0, stream>>>(dst, deg, eslot, E);
    scan_partial<<<B, 256, 0, stream>>>(deg, partial, N);
    scan_block<<<1, 256, 0, stream>>>(partial, B);
    scan_final<<<B, 256, 0, stream>>>(deg, partial, off, deg_inv, N);
    fill_csr<<<(E + 255) / 256, 256, 0, stream>>>(src, dst, off, eslot, csr, E);

    int aggGrid = (N + 3) / 4;

    // layer 1 (K=128)
    gemm_dual<128><<<512, 512, 0, stream>>>(x, Wl1, Wr1, bl1, y, s, N);
    agg_relu<<<aggGrid, 256, 0, stream>>>(y, s, csr, off, deg_inv, h, N);
    // layer 2 (K=64)
    gemm_dual<64><<<512, 512, 0, stream>>>(h, Wl2, Wr2, bl2, y, s, N);
    agg_relu<<<aggGrid, 256, 0, stream>>>(y, s, csr, off, deg_inv, h, N);
    // layer 3 (K=64) + classifier fused into aggregation
    gemm_dual<64><<<512, 512, 0, stream>>>(h, Wl3, Wr3, bl3, y, s, N);
    agg_classify<<<aggGrid, 256, 0, stream>>>(y, s, csr, off, deg_inv, Wc, bc, out, N);
}

// Round 10
// 507.505 us; speedup vs baseline: 1.2217x; 1.2217x over previous
//
#include <hip/hip_runtime.h>
#include <hip/hip_bf16.h>

// FraudGNN: 3x SAGEConv(mean) + ReLU + linear classifier.
// Structure: transform-then-aggregate; CSR build (1 atomic pass); gather-side
// aggregation; classifier fused into layer-3 agg.
// Measured history:
//  R6 (256thr, X-LDS, F=1/R=4, scalar W reads): gemm128=101us VALU 52% -> LDS-issue-bound.
//  R9 (512thr, X via global broadcast loads):   gemm128=140us VALU 33% -> REGRESSION:
//     broadcast loads pay full 64-lane return cost; VGPR=60 starved load pipelining.
// R10: revert to X-in-LDS; register tile F=2 feats x R=4 rows per thread
//   (LDS floats/FMA 0.75->0.5), W read as b128 from XOR-swizzled LDS
//   (quad ^= (f>>1)&(QPR-1)), 64-row tiles (barriers /4), float2 coalesced C-write.
//   LDS: K=128: 96KB (1 blk/CU, 8 waves); K=64: 48KB (3 blk/CU, 24 waves).

// ---------------- degree count + slot assignment (single atomic pass) --------
__global__ __launch_bounds__(256) void count_deg_slot(const int* __restrict__ dst,
                                                      int* __restrict__ deg,
                                                      int* __restrict__ eslot, int nE) {
    int e = blockIdx.x * 256 + threadIdx.x;
    if (e < nE) eslot[e] = atomicAdd(&deg[dst[e]], 1);
}

// ---------------- 3-phase exclusive scan over deg (N<=2048*256) ----------------
__global__ __launch_bounds__(256) void scan_partial(const int* __restrict__ deg,
                                                    int* __restrict__ partial, int n) {
    __shared__ int red[256];
    int base = blockIdx.x * 2048;
    int t = threadIdx.x;
    int sum = 0;
    for (int j = 0; j < 8; ++j) {
        int i = base + t + 256 * j;
        if (i < n) sum += deg[i];
    }
    red[t] = sum;
    __syncthreads();
    for (int o = 128; o; o >>= 1) {
        if (t < o) red[t] += red[t + o];
        __syncthreads();
    }
    if (t == 0) partial[blockIdx.x] = red[0];
}

__global__ __launch_bounds__(256) void scan_block(int* __restrict__ partial, int B) {
    __shared__ int tmp[256];
    int t = threadIdx.x;
    int orig = (t < B) ? partial[t] : 0;
    tmp[t] = orig;
    __syncthreads();
    for (int o = 1; o < 256; o <<= 1) {
        int v = (t >= o) ? tmp[t - o] : 0;
        __syncthreads();
        tmp[t] += v;
        __syncthreads();
    }
    if (t < B) partial[t] = tmp[t] - orig;  // exclusive
}

__global__ __launch_bounds__(256) void scan_final(const int* __restrict__ deg,
                                                  const int* __restrict__ partial,
                                                  int* __restrict__ off,
                                                  float* __restrict__ deg_inv, int n) {
    __shared__ int lds[2048];
    __shared__ int tsum[256];
    int base = blockIdx.x * 2048;
    int t = threadIdx.x;
    for (int j = 0; j < 8; ++j) {
        int i = base + t + 256 * j;
        lds[t + 256 * j] = (i < n) ? deg[i] : 0;
    }
    __syncthreads();
    int loc[8];
    int s0 = 0;
    for (int j = 0; j < 8; ++j) {
        loc[j] = s0;
        s0 += lds[t * 8 + j];
    }
    int orig = s0;
    tsum[t] = s0;
    __syncthreads();
    for (int o = 1; o < 256; o <<= 1) {
        int v = (t >= o) ? tsum[t - o] : 0;
        __syncthreads();
        tsum[t] += v;
        __syncthreads();
    }
    int tpre = tsum[t] - orig + partial[blockIdx.x];
    for (int j = 0; j < 8; ++j) {
        int i = base + t * 8 + j;
        if (i < n) {
            int d = lds[t * 8 + j];
            int ex = tpre + loc[j];
            off[i] = ex;
            deg_inv[i] = 1.0f / (float)((d > 1) ? d : 1);
            if (i == n - 1) off[n] = ex + d;
        }
    }
}

// ---------------- CSR fill (atomic-free: slot precomputed) ----------------
__global__ __launch_bounds__(256) void fill_csr(const int* __restrict__ src,
                                                const int* __restrict__ dst,
                                                const int* __restrict__ off,
                                                const int* __restrict__ eslot,
                                                int* __restrict__ csr, int nE) {
    int e = blockIdx.x * 256 + threadIdx.x;
    if (e >= nE) return;
    csr[off[dst[e]] + eslot[e]] = src[e];
}

// ---------------- dual GEMM: Y = X @ Wl^T ; S = X @ Wr^T + bl ----------------
// X:[n,K], Wl/Wr:[64,K], Y/S:[n,64].
// 512 threads: p = t&31 -> features (2p, 2p+1); s = t>>5 -> 4 rows each
// (64-row tile). Register tile F=2 x R=4: per kq (4 k's) per thread:
//   4 x b128 W reads (XOR-swizzled, conflict-mitigated) +
//   4 x b128 X broadcast reads (wave has 2 distinct addrs -> 2-way = free)
//   feeding 64 FMA instrs -> LDS instr:FMA = 1:8 (R6 was 1:5.3 w/ scalar W).
// W swizzle: quad' = quad ^ ((f>>1) & (QPR-1)); bijective, read uses same XOR.
template <int K>
__global__ __launch_bounds__(512, 4) void gemm_dual(const float* __restrict__ X,
                                                    const float* __restrict__ Wl,
                                                    const float* __restrict__ Wr,
                                                    const float* __restrict__ bl,
                                                    float* __restrict__ Y,
                                                    float* __restrict__ S, int nNodes) {
    constexpr int QPR = K / 4;  // float4 quads per row
    __shared__ float4 wl_s[64 * QPR];
    __shared__ float4 wr_s[64 * QPR];
    __shared__ float4 x_s[64 * QPR];
    const int t = threadIdx.x;

    // stage W swizzled (one-time)
    const float4* __restrict__ Wl4 = reinterpret_cast<const float4*>(Wl);
    const float4* __restrict__ Wr4 = reinterpret_cast<const float4*>(Wr);
    for (int i = t; i < 64 * QPR; i += 512) {
        int f = i / QPR, q = i % QPR;
        int qs = q ^ ((f >> 1) & (QPR - 1));
        wl_s[f * QPR + qs] = Wl4[i];
        wr_s[f * QPR + qs] = Wr4[i];
    }

    const int p = t & 31;        // feature pair -> features 2p, 2p+1
    const int s = t >> 5;        // row slot 0..15 -> rows s*4..s*4+3
    const int fe0 = 2 * p;
    const int pm = p & (QPR - 1);          // swizzle term ((fe>>1) = p for both feats)
    const float2 blv = reinterpret_cast<const float2*>(bl)[p];
    const float4* __restrict__ Xv = reinterpret_cast<const float4*>(X);
    const float4* __restrict__ wlA = wl_s + (size_t)fe0 * QPR;
    const float4* __restrict__ wlB = wl_s + (size_t)(fe0 + 1) * QPR;
    const float4* __restrict__ wrA = wr_s + (size_t)fe0 * QPR;
    const float4* __restrict__ wrB = wr_s + (size_t)(fe0 + 1) * QPR;

    for (int tile = blockIdx.x * 64; tile < nNodes; tile += gridDim.x * 64) {
        __syncthreads();  // protect x_s reuse (also orders first W reads after stage)
        for (int i = t; i < 64 * QPR; i += 512) {
            int r = i / QPR, q = i % QPR;
            int row = tile + r;
            row = (row < nNodes) ? row : (nNodes - 1);  // clamp; stores guarded
            x_s[i] = Xv[(size_t)row * QPR + q];
        }
        __syncthreads();

        float2 accY[4], accS[4];
#pragma unroll
        for (int j = 0; j < 4; ++j) {
            accY[j] = make_float2(0.f, 0.f);
            accS[j] = make_float2(0.f, 0.f);
        }
#pragma unroll 2
        for (int kq = 0; kq < QPR; ++kq) {
            const int qs = kq ^ pm;
            float4 wl0 = wlA[qs];
            float4 wl1 = wlB[qs];
            float4 wr0 = wrA[qs];
            float4 wr1 = wrB[qs];
#pragma unroll
            for (int j = 0; j < 4; ++j) {
                float4 xv = x_s[(s * 4 + j) * QPR + kq];  // 2 addrs/wave -> free
                accY[j].x = fmaf(xv.x, wl0.x, accY[j].x);
                accY[j].x = fmaf(xv.y, wl0.y, accY[j].x);
                accY[j].x = fmaf(xv.z, wl0.z, accY[j].x);
                accY[j].x = fmaf(xv.w, wl0.w, accY[j].x);
                accY[j].y = fmaf(xv.x, wl1.x, accY[j].y);
                accY[j].y = fmaf(xv.y, wl1.y, accY[j].y);
                accY[j].y = fmaf(xv.z, wl1.z, accY[j].y);
                accY[j].y = fmaf(xv.w, wl1.w, accY[j].y);
                accS[j].x = fmaf(xv.x, wr0.x, accS[j].x);
                accS[j].x = fmaf(xv.y, wr0.y, accS[j].x);
                accS[j].x = fmaf(xv.z, wr0.z, accS[j].x);
                accS[j].x = fmaf(xv.w, wr0.w, accS[j].x);
                accS[j].y = fmaf(xv.x, wr1.x, accS[j].y);
                accS[j].y = fmaf(xv.y, wr1.y, accS[j].y);
                accS[j].y = fmaf(xv.z, wr1.z, accS[j].y);
                accS[j].y = fmaf(xv.w, wr1.w, accS[j].y);
            }
        }

        const int r0 = tile + s * 4;
#pragma unroll
        for (int j = 0; j < 4; ++j) {
            int row = r0 + j;
            if (row < nNodes) {
                reinterpret_cast<float2*>(Y + (size_t)row * 64)[p] = accY[j];
                reinterpret_cast<float2*>(S + (size_t)row * 64)[p] =
                    make_float2(accS[j].x + blv.x, accS[j].y + blv.y);
            }
        }
    }
}

// ---------------- aggregation core: sum_neighbors(Y) as float4 ----------------
// wave = 16 feature-quads x 4 edge-quarters. Quarter q reads row src[4j+q] as
// float4 (16 lanes x 16 B = 256 B, coalesced). ILP ladder: x4-unrolled block
// (4 loads in flight), then x2, then x1.
__device__ __forceinline__ float4 agg_core(const float4* __restrict__ Yv,
                                           const int* __restrict__ csr,
                                           int e0, int e1, int lane) {
    const int q = lane >> 4;         // edge quarter 0..3
    const int fq = lane & 15;        // feature quad
    float4 acc = make_float4(0.f, 0.f, 0.f, 0.f);
    for (int base = e0; base < e1; base += 64) {
        int cnt = min(64, e1 - base);
        int mysrc = (lane < cnt) ? csr[base + lane] : 0;
        int nFull = cnt >> 2;
        int j = 0;
        for (; j + 4 <= nFull; j += 4) {   // 4 outstanding dwordx4 loads
            int s0 = __shfl(mysrc, 4 * j + q);
            int s1 = __shfl(mysrc, 4 * j + 4 + q);
            int s2 = __shfl(mysrc, 4 * j + 8 + q);
            int s3 = __shfl(mysrc, 4 * j + 12 + q);
            float4 v0 = Yv[(size_t)s0 * 16 + fq];
            float4 v1 = Yv[(size_t)s1 * 16 + fq];
            float4 v2 = Yv[(size_t)s2 * 16 + fq];
            float4 v3 = Yv[(size_t)s3 * 16 + fq];
            acc.x += v0.x; acc.y += v0.y; acc.z += v0.z; acc.w += v0.w;
            acc.x += v1.x; acc.y += v1.y; acc.z += v1.z; acc.w += v1.w;
            acc.x += v2.x; acc.y += v2.y; acc.z += v2.z; acc.w += v2.w;
            acc.x += v3.x; acc.y += v3.y; acc.z += v3.z; acc.w += v3.w;
        }
        if (j + 2 <= nFull) {              // 2 outstanding
            int s0 = __shfl(mysrc, 4 * j + q);
            int s1 = __shfl(mysrc, 4 * j + 4 + q);
            float4 v0 = Yv[(size_t)s0 * 16 + fq];
            float4 v1 = Yv[(size_t)s1 * 16 + fq];
            acc.x += v0.x; acc.y += v0.y; acc.z += v0.z; acc.w += v0.w;
            acc.x += v1.x; acc.y += v1.y; acc.z += v1.z; acc.w += v1.w;
            j += 2;
        }
        if (j < nFull) {                   // last full quad
            int sj = __shfl(mysrc, 4 * j + q);
            float4 v = Yv[(size_t)sj * 16 + fq];
            acc.x += v.x; acc.y += v.y; acc.z += v.z; acc.w += v.w;
        }
        int rem = cnt & 3;
        if (rem) {
            int sj = __shfl(mysrc, 4 * nFull + q);  // idx <= 63 always
            if (q < rem) {
                float4 v = Yv[(size_t)sj * 16 + fq];
                acc.x += v.x; acc.y += v.y; acc.z += v.z; acc.w += v.w;
            }
        }
    }
    // combine quarter partials: after xor16 + xor32 every lane has the full sum
    acc.x += __shfl_xor(acc.x, 16); acc.y += __shfl_xor(acc.y, 16);
    acc.z += __shfl_xor(acc.z, 16); acc.w += __shfl_xor(acc.w, 16);
    acc.x += __shfl_xor(acc.x, 32); acc.y += __shfl_xor(acc.y, 32);
    acc.z += __shfl_xor(acc.z, 32); acc.w += __shfl_xor(acc.w, 32);
    return acc;  // lanes 0-15 used for epilogue (feature quad fq)
}

// ---------------- aggregation: H = relu(mean_neighbors(Y) + S) ----------------
__global__ __launch_bounds__(256) void agg_relu(const float* __restrict__ Y,
                                                const float* __restrict__ S,
                                                const int* __restrict__ csr,
                                                const int* __restrict__ off,
                                                const float* __restrict__ deg_inv,
                                                float* __restrict__ H, int nNodes) {
    int wave = threadIdx.x >> 6;
    int lane = threadIdx.x & 63;
    int n = blockIdx.x * 4 + wave;
    if (n >= nNodes) return;
    int e0 = off[n], e1 = off[n + 1];
    // prefetch epilogue operands: independent of the gather, hide under it
    float di = deg_inv[n];
    float4 sv = ((const float4*)S)[(size_t)n * 16 + (lane & 15)];
    float4 acc = agg_core((const float4*)Y, csr, e0, e1, lane);
    if (lane < 16) {
        float4 h;
        h.x = fmaxf(fmaf(acc.x, di, sv.x), 0.f);
        h.y = fmaxf(fmaf(acc.y, di, sv.y), 0.f);
        h.z = fmaxf(fmaf(acc.z, di, sv.z), 0.f);
        h.w = fmaxf(fmaf(acc.w, di, sv.w), 0.f);
        ((float4*)H)[(size_t)n * 16 + lane] = h;
    }
}

// ---------------- layer-3 aggregation + classifier fused ----------------
__global__ __launch_bounds__(256) void agg_classify(const float* __restrict__ Y,
                                                    const float* __restrict__ S,
                                                    const int* __restrict__ csr,
                                                    const int* __restrict__ off,
                                                    const float* __restrict__ deg_inv,
                                                    const float* __restrict__ Wc,
                                                    const float* __restrict__ bc,
                                                    float* __restrict__ out, int nNodes) {
    int wave = threadIdx.x >> 6;
    int lane = threadIdx.x & 63;
    int n = blockIdx.x * 4 + wave;
    if (n >= nNodes) return;
    int e0 = off[n], e1 = off[n + 1];
    float di = deg_inv[n];
    float4 sv = ((const float4*)S)[(size_t)n * 16 + (lane & 15)];
    float4 wc = ((const float4*)Wc)[lane & 15];
    float bias = bc[0];
    float4 acc = agg_core((const float4*)Y, csr, e0, e1, lane);
    if (lane < 16) {
        float hx = fmaxf(fmaf(acc.x, di, sv.x), 0.f);
        float hy = fmaxf(fmaf(acc.y, di, sv.y), 0.f);
        float hz = fmaxf(fmaf(acc.z, di, sv.z), 0.f);
        float hw = fmaxf(fmaf(acc.w, di, sv.w), 0.f);
        float c = hx * wc.x + hy * wc.y + hz * wc.z + hw * wc.w;
#pragma unroll
        for (int o = 8; o; o >>= 1) c += __shfl_xor(c, o);  // within 16-lane group
        if (lane == 0) out[n] = c + bias;
    }
}

extern "C" void kernel_launch(void* const* d_in, const int* in_sizes, int n_in,
                              void* d_out, int out_size, void* d_ws, size_t ws_size,
                              hipStream_t stream) {
    const float* x   = (const float*)d_in[0];
    const int*   ei  = (const int*)d_in[1];
    const float* Wl1 = (const float*)d_in[2];
    const float* bl1 = (const float*)d_in[3];
    const float* Wr1 = (const float*)d_in[4];
    const float* Wl2 = (const float*)d_in[5];
    const float* bl2 = (const float*)d_in[6];
    const float* Wr2 = (const float*)d_in[7];
    const float* Wl3 = (const float*)d_in[8];
    const float* bl3 = (const float*)d_in[9];
    const float* Wr3 = (const float*)d_in[10];
    const float* Wc  = (const float*)d_in[11];
    const float* bc  = (const float*)d_in[12];
    float* out = (float*)d_out;

    const int N = in_sizes[0] / 128;   // 100000
    const int E = in_sizes[1] / 2;     // 1600000
    const int* src = ei;
    const int* dst = ei + E;

    // workspace carve (256B aligned); total ~91 MB
    char* p = (char*)d_ws;
    auto alloc = [&](size_t bytes) -> void* {
        char* r = p;
        p += (bytes + 255) & ~(size_t)255;
        return (void*)r;
    };
    int*   deg     = (int*)alloc((size_t)N * 4);
    int*   off     = (int*)alloc((size_t)(N + 1) * 4);
    int*   eslot   = (int*)alloc((size_t)E * 4);
    int*   partial = (int*)alloc(256 * 4);
    int*   csr     = (int*)alloc((size_t)E * 4);
    float* deg_inv = (float*)alloc((size_t)N * 4);
    float* y       = (float*)alloc((size_t)N * 64 * 4);
    float* s       = (float*)alloc((size_t)N * 64 * 4);
    float* h       = (float*)alloc((size_t)N * 64 * 4);

    hipMemsetAsync(deg, 0, (size_t)N * 4, stream);

    const int B = (N + 2047) / 2048;  // 49 scan blocks

    count_deg_slot<<<(E + 255) / 256, 256, 0, stream>>>(dst, deg, eslot, E);
    scan_partial<<<B, 256, 0, stream>>>(deg, partial, N);
    scan_block<<<1, 256, 0, stream>>>(partial, B);
    scan_final<<<B, 256, 0, stream>>>(deg, partial, off, deg_inv, N);
    fill_csr<<<(E + 255) / 256, 256, 0, stream>>>(src, dst, off, eslot, csr, E);

    int aggGrid = (N + 3) / 4;

    // layer 1 (K=128): 96KB LDS -> 1 block/CU; grid 512 => ~3 tiles/block
    gemm_dual<128><<<512, 512, 0, stream>>>(x, Wl1, Wr1, bl1, y, s, N);
    agg_relu<<<aggGrid, 256, 0, stream>>>(y, s, csr, off, deg_inv, h, N);
    // layer 2 (K=64): 48KB LDS -> 3 blocks/CU; grid 768
    gemm_dual<64><<<768, 512, 0, stream>>>(h, Wl2, Wr2, bl2, y, s, N);
    agg_relu<<<aggGrid, 256, 0, stream>>>(y, s, csr, off, deg_inv, h, N);
    // layer 3 (K=64) + classifier fused into aggregation
    gemm_dual<64><<<768, 512, 0, stream>>>(h, Wl3, Wr3, bl3, y, s, N);
    agg_classify<<<aggGrid, 256, 0, stream>>>(y, s, csr, off, deg_inv, Wc, bc, out, N);
}